// Round 4
// baseline (854.829 us; speedup 1.0000x reference)
//
#include <hip/hip_runtime.h>

typedef unsigned short u16;
typedef __attribute__((ext_vector_type(8))) unsigned short v8u16;
typedef __attribute__((ext_vector_type(4))) unsigned short v4u16;
typedef __attribute__((ext_vector_type(8))) __bf16 v8bf;
typedef __attribute__((ext_vector_type(4))) float v4f;

#define NN 50000
#define EE 150000

__device__ inline float b2f(u16 u) {
    union { unsigned int i; float f; } x; x.i = ((unsigned int)u) << 16; return x.f;
}
__device__ inline u16 f2b(float f) {
    union { float f; unsigned int i; } x; x.f = f;
    unsigned int r = x.i + 0x7FFFu + ((x.i >> 16) & 1u);
    return (u16)(r >> 16);
}
__device__ inline float wred(float v) {
    v += __shfl_down(v, 32, 64);
    v += __shfl_down(v, 16, 64);
    v += __shfl_down(v, 8, 64);
    v += __shfl_down(v, 4, 64);
    v += __shfl_down(v, 2, 64);
    v += __shfl_down(v, 1, 64);
    return v;
}

// ---------------- weight prep ----------------

// Wt[n*K+k] = bf16(W[k*N+n])   (W fp32 row-major [K,N])
__global__ void transpose_f2b(const float* __restrict__ W, u16* __restrict__ Wt, int K, int N) {
    int idx = blockIdx.x * blockDim.x + threadIdx.x;
    if (idx >= K * N) return;
    int n = idx % N, k = idx / N;
    Wt[(size_t)n * K + k] = f2b(W[idx]);
}

// v[r] = sum_c W[r*C+c]*a[c]  (fp32, one wave per row)
__global__ void wv_f32(const float* __restrict__ W, const float* __restrict__ a,
                       float* __restrict__ v, int R, int C) {
    int row = (blockIdx.x * blockDim.x + threadIdx.x) >> 6;
    int lane = threadIdx.x & 63;
    if (row >= R) return;
    float s = 0.f;
    int c0 = lane * 8;
    if (c0 < C) {
        const float* wp = W + (size_t)row * C + c0;
        v4f w0 = *(const v4f*)wp;
        v4f w1 = *(const v4f*)(wp + 4);
        v4f a0 = *(const v4f*)(a + c0);
        v4f a1 = *(const v4f*)(a + c0 + 4);
#pragma unroll
        for (int j = 0; j < 4; ++j) s += w0[j] * a0[j] + w1[j] * a1[j];
    }
    s = wred(s);
    if (lane == 0) v[row] = s;
}

// asrc[n]=X[n,:].vs ; adst[n]=X[n,:].vd  (fp32 X, inner dim 512, one wave/node)
__global__ void alpha_pair_f32(const float* __restrict__ X, const float* __restrict__ vs,
                               const float* __restrict__ vd, float* __restrict__ as_,
                               float* __restrict__ ad_, int Nn) {
    int w = (blockIdx.x * blockDim.x + threadIdx.x) >> 6;
    int lane = threadIdx.x & 63;
    if (w >= Nn) return;
    const float* xp = X + (size_t)w * 512 + lane * 8;
    v4f x0 = *(const v4f*)xp;
    v4f x1 = *(const v4f*)(xp + 4);
    const float* vsp = vs + lane * 8;
    const float* vdp = vd + lane * 8;
    float s1 = 0.f, s2 = 0.f;
#pragma unroll
    for (int j = 0; j < 4; ++j) {
        s1 += x0[j] * vsp[j] + x1[j] * vsp[j + 4];
        s2 += x0[j] * vdp[j] + x1[j] * vdp[j + 4];
    }
    s1 = wred(s1);
    s2 = wred(s2);
    if (lane == 0) { as_[w] = s1; ad_[w] = s2; }
}

// bf16-X variant (layer 2: X = hmid bf16)
__global__ void alpha_pair_bf16(const u16* __restrict__ X, const float* __restrict__ vs,
                                const float* __restrict__ vd, float* __restrict__ as_,
                                float* __restrict__ ad_, int Nn) {
    int w = (blockIdx.x * blockDim.x + threadIdx.x) >> 6;
    int lane = threadIdx.x & 63;
    if (w >= Nn) return;
    v8u16 xv = *(const v8u16*)(X + (size_t)w * 512 + lane * 8);
    const float* vsp = vs + lane * 8;
    const float* vdp = vd + lane * 8;
    float s1 = 0.f, s2 = 0.f;
#pragma unroll
    for (int j = 0; j < 8; ++j) {
        float xf = b2f(xv[j]);
        s1 += xf * vsp[j];
        s2 += xf * vdp[j];
    }
    s1 = wred(s1);
    s2 = wred(s2);
    if (lane == 0) { as_[w] = s1; ad_[w] = s2; }
}

// ---------------- CSR build (int atomics only) ----------------

__global__ void deg_kernel(const int* __restrict__ dst, int* __restrict__ deg, int E) {
    int e = blockIdx.x * blockDim.x + threadIdx.x;
    if (e < E) atomicAdd(&deg[dst[e]], 1);
}

__global__ void exscan_kernel(const int* __restrict__ deg, int* __restrict__ rowptr, int Nn) {
    __shared__ int ls[1024];
    int tid = threadIdx.x;
    int per = (Nn + 1023) / 1024;
    int base = tid * per;
    int s = 0;
    for (int i = 0; i < per; ++i) if (base + i < Nn) s += deg[base + i];
    ls[tid] = s;
    __syncthreads();
    for (int off = 1; off < 1024; off <<= 1) {
        int v = (tid >= off) ? ls[tid - off] : 0;
        __syncthreads();
        ls[tid] += v;
        __syncthreads();
    }
    int run = ls[tid] - s;
    for (int i = 0; i < per; ++i) {
        if (base + i < Nn) { rowptr[base + i] = run; run += deg[base + i]; }
    }
    if (tid == 1023) rowptr[Nn] = run;
}

__global__ void fill_kernel(const int* __restrict__ dst, const int* __restrict__ rowptr,
                            int* __restrict__ cursor, int* __restrict__ eid, int E) {
    int e = blockIdx.x * blockDim.x + threadIdx.x;
    if (e >= E) return;
    int d = dst[e];
    int pos = rowptr[d] + atomicAdd(&cursor[d], 1);
    eid[pos] = e;
}

// ---------------- pull-based dual-edge-set GAT aggregate ----------------
// one wave per destination node; G[d,:] = sum over 2 edge sets of
// softmax-weighted H[src,:] plus 2*bias (fp32). CV = C/64 (8 or 4).
template <int CV>
__global__ void gat_pull(const int* __restrict__ src1, const int* __restrict__ rp1,
                         const int* __restrict__ eid1,
                         const int* __restrict__ src2, const int* __restrict__ rp2,
                         const int* __restrict__ eid2,
                         const float* __restrict__ asrc, const float* __restrict__ adst,
                         const u16* __restrict__ H, const float* __restrict__ bias,
                         u16* __restrict__ G, int Nn) {
    const int C = CV * 64;
    int d = (blockIdx.x * blockDim.x + threadIdx.x) >> 6;
    int lane = threadIdx.x & 63;
    if (d >= Nn) return;
    float acc[CV];
#pragma unroll
    for (int j = 0; j < CV; ++j) acc[j] = 0.f;
    float ad = adst[d];
#pragma unroll
    for (int set = 0; set < 2; ++set) {
        const int* src = set ? src2 : src1;
        const int* rp  = set ? rp2  : rp1;
        const int* eid = set ? eid2 : eid1;
        int beg = rp[d], end = rp[d + 1];
        float ssum = 0.f;
        for (int i = beg; i < end; ++i) {
            float t = asrc[src[eid[i]]] + ad;
            t = t > 0.f ? t : 0.2f * t;
            ssum += __expf(fminf(t, 60.f));
        }
        float inv = 1.f / (ssum + 1e-16f);
        for (int i = beg; i < end; ++i) {
            int s = src[eid[i]];
            float t = asrc[s] + ad;
            t = t > 0.f ? t : 0.2f * t;
            float a = __expf(fminf(t, 60.f)) * inv;
            const u16* hp = H + (size_t)s * C + lane * CV;
            if constexpr (CV == 8) {
                v8u16 hv = *(const v8u16*)hp;
#pragma unroll
                for (int j = 0; j < 8; ++j) acc[j] += a * b2f(hv[j]);
            } else {
                v4u16 hv = *(const v4u16*)hp;
#pragma unroll
                for (int j = 0; j < 4; ++j) acc[j] += a * b2f(hv[j]);
            }
        }
    }
    const float* bp = bias + lane * CV;
    u16* gp = G + (size_t)d * C + lane * CV;
    if constexpr (CV == 8) {
        v8u16 o;
#pragma unroll
        for (int j = 0; j < 8; ++j) o[j] = f2b(acc[j] + 2.f * bp[j]);
        *(v8u16*)gp = o;
    } else {
        v4u16 o;
#pragma unroll
        for (int j = 0; j < 4; ++j) o[j] = f2b(acc[j] + 2.f * bp[j]);
        *(v4u16*)gp = o;
    }
}

// ---------------- MFMA GEMM ----------------
// C[M,N] = A[M,K] @ Bt[N,K]^T. A fp32 (AF32=1, converted inline) or bf16.
// Output fp32 (outf32) or bf16. fp32 accumulate, optional fp32 bias / relu.
template <int AF32>
__global__ __launch_bounds__(256, 2) void gemm_bf16(
    const void* __restrict__ Av, const u16* __restrict__ Bt, void* __restrict__ Cv,
    int M, int N, int K, const float* __restrict__ bias, int relu, int outf32) {
    __shared__ u16 As[128 * 40];
    __shared__ u16 Bs[128 * 40];
    const int tid = threadIdx.x;
    const int lane = tid & 63;
    const int wid = tid >> 6;
    const int wm = wid >> 1;
    const int wn = wid & 1;
    const int quad = lane >> 4;
    const int l16 = lane & 15;
    const int tileM = blockIdx.x * 128;
    const int tileN = blockIdx.y * 128;

    v4f acc[4][4];
#pragma unroll
    for (int i = 0; i < 4; ++i)
#pragma unroll
        for (int j = 0; j < 4; ++j) acc[i][j] = v4f{0.f, 0.f, 0.f, 0.f};

    for (int k0 = 0; k0 < K; k0 += 32) {
#pragma unroll
        for (int r = 0; r < 2; ++r) {
            int idx = r * 256 + tid;
            int row = idx >> 2;
            int col = (idx & 3) << 3;
            int ga = tileM + row; ga = ga < M ? ga : M - 1;
            if (AF32) {
                const float* ap = (const float*)Av + (size_t)ga * K + k0 + col;
                v4f f0 = *(const v4f*)ap;
                v4f f1 = *(const v4f*)(ap + 4);
                v8u16 o;
#pragma unroll
                for (int j = 0; j < 4; ++j) { o[j] = f2b(f0[j]); o[j + 4] = f2b(f1[j]); }
                *(v8u16*)&As[row * 40 + col] = o;
            } else {
                *(v8u16*)&As[row * 40 + col] =
                    *(const v8u16*)((const u16*)Av + (size_t)ga * K + k0 + col);
            }
            *(v8u16*)&Bs[row * 40 + col] = *(const v8u16*)(Bt + (size_t)(tileN + row) * K + k0 + col);
        }
        __syncthreads();
        v8bf af[4], bfr[4];
#pragma unroll
        for (int i = 0; i < 4; ++i)
            af[i] = __builtin_bit_cast(v8bf, *(const v8u16*)&As[(wm * 64 + i * 16 + l16) * 40 + quad * 8]);
#pragma unroll
        for (int i = 0; i < 4; ++i)
            bfr[i] = __builtin_bit_cast(v8bf, *(const v8u16*)&Bs[(wn * 64 + i * 16 + l16) * 40 + quad * 8]);
#pragma unroll
        for (int mi = 0; mi < 4; ++mi)
#pragma unroll
            for (int ni = 0; ni < 4; ++ni)
                acc[mi][ni] = __builtin_amdgcn_mfma_f32_16x16x32_bf16(af[mi], bfr[ni], acc[mi][ni], 0, 0, 0);
        __syncthreads();
    }

#pragma unroll
    for (int mi = 0; mi < 4; ++mi)
#pragma unroll
        for (int ni = 0; ni < 4; ++ni) {
            int col = tileN + wn * 64 + ni * 16 + l16;
            float bb = bias ? bias[col] : 0.f;
            int row0 = tileM + wm * 64 + mi * 16 + quad * 4;
#pragma unroll
            for (int r = 0; r < 4; ++r) {
                int row = row0 + r;
                if (row < M) {
                    float v = acc[mi][ni][r] + bb;
                    if (relu) v = fmaxf(v, 0.f);
                    if (outf32) ((float*)Cv)[(size_t)row * N + col] = v;
                    else        ((u16*)Cv)[(size_t)row * N + col] = f2b(v);
                }
            }
        }
}

// ---------------- launch ----------------

extern "C" void kernel_launch(void* const* d_in, const int* in_sizes, int n_in,
                              void* d_out, int out_size, void* d_ws, size_t ws_size,
                              hipStream_t stream) {
    const float* x  = (const float*)d_in[0];
    const int* ei1  = (const int*)d_in[1];
    const int* ei2  = (const int*)d_in[2];
    const float* W1s = (const float*)d_in[3];
    const float* W1d = (const float*)d_in[4];
    const float* a1s = (const float*)d_in[5];
    const float* a1d = (const float*)d_in[6];
    const float* b1  = (const float*)d_in[7];
    const float* Wl1 = (const float*)d_in[8];
    const float* bl1 = (const float*)d_in[9];
    const float* W2s = (const float*)d_in[10];
    const float* W2d = (const float*)d_in[11];
    const float* a2s = (const float*)d_in[12];
    const float* a2d = (const float*)d_in[13];
    const float* b2  = (const float*)d_in[14];
    const float* Wl2 = (const float*)d_in[15];
    const float* bl2 = (const float*)d_in[16];
    float* out = (float*)d_out;

    char* ws = (char*)d_ws;
    size_t off = 0;
    auto alloc = [&](size_t b) { void* p = ws + off; off = (off + b + 255) & ~(size_t)255; return p; };
    u16* bufA   = (u16*)alloc((size_t)NN * 512 * 2);   // Hsrc1 -> hmid
    u16* bufB   = (u16*)alloc((size_t)NN * 512 * 2);   // g1 -> Hsrc2(lower)+g2(upper)
    int* rp1    = (int*)alloc((size_t)(NN + 1) * 4);
    int* rp2    = (int*)alloc((size_t)(NN + 1) * 4);
    int* eid1   = (int*)alloc((size_t)EE * 4);
    int* eid2   = (int*)alloc((size_t)EE * 4);
    int* deg    = (int*)alloc((size_t)NN * 4);         // reused as cursor
    float* asrc = (float*)alloc((size_t)NN * 4);
    float* adst = (float*)alloc((size_t)NN * 4);
    float* v1s  = (float*)alloc(512 * 4);
    float* v1d  = (float*)alloc(512 * 4);
    float* v2s  = (float*)alloc(512 * 4);
    float* v2d  = (float*)alloc(512 * 4);
    u16* Wt1s   = (u16*)alloc((size_t)512 * 512 * 2);
    u16* Wtl1   = (u16*)alloc((size_t)512 * 512 * 2);
    u16* Wt2s   = (u16*)alloc((size_t)512 * 256 * 2);
    u16* Wtl2   = (u16*)alloc((size_t)256 * 256 * 2);
    u16* g2buf  = bufB + (size_t)NN * 256;

    // CSR build for both edge sets (dst = row 1 of edge_index)
    const int* eis[2] = { ei1, ei2 };
    int* rps[2] = { rp1, rp2 };
    int* eids[2] = { eid1, eid2 };
    for (int s = 0; s < 2; ++s) {
        hipMemsetAsync(deg, 0, (size_t)NN * 4, stream);
        deg_kernel<<<(EE + 255) / 256, 256, 0, stream>>>(eis[s] + EE, deg, EE);
        exscan_kernel<<<1, 1024, 0, stream>>>(deg, rps[s], NN);
        hipMemsetAsync(deg, 0, (size_t)NN * 4, stream);
        fill_kernel<<<(EE + 255) / 256, 256, 0, stream>>>(eis[s] + EE, rps[s], deg, eids[s], EE);
    }

    // weight prep: transpose+downcast to bf16, and fp32 GEMV vectors
    transpose_f2b<<<(512 * 512 + 255) / 256, 256, 0, stream>>>(W1s, Wt1s, 512, 512);
    transpose_f2b<<<(512 * 512 + 255) / 256, 256, 0, stream>>>(Wl1, Wtl1, 512, 512);
    transpose_f2b<<<(512 * 256 + 255) / 256, 256, 0, stream>>>(W2s, Wt2s, 512, 256);
    transpose_f2b<<<(256 * 256 + 255) / 256, 256, 0, stream>>>(Wl2, Wtl2, 256, 256);
    wv_f32<<<128, 256, 0, stream>>>(W1s, a1s, v1s, 512, 512);
    wv_f32<<<128, 256, 0, stream>>>(W1d, a1d, v1d, 512, 512);
    wv_f32<<<128, 256, 0, stream>>>(W2s, a2s, v2s, 512, 256);
    wv_f32<<<128, 256, 0, stream>>>(W2d, a2d, v2d, 512, 256);

    // ---- layer 1 ----
    alpha_pair_f32<<<(NN + 3) / 4, 256, 0, stream>>>(x, v1s, v1d, asrc, adst, NN);
    gemm_bf16<1><<<dim3(391, 4), 256, 0, stream>>>(x, Wt1s, bufA, NN, 512, 512, nullptr, 0, 0);
    gat_pull<8><<<(NN + 3) / 4, 256, 0, stream>>>(ei1, rp1, eid1, ei2, rp2, eid2,
                                                  asrc, adst, bufA, b1, bufB, NN);
    gemm_bf16<0><<<dim3(391, 4), 256, 0, stream>>>(bufB, Wtl1, bufA, NN, 512, 512, bl1, 1, 0);

    // ---- layer 2 ----
    alpha_pair_bf16<<<(NN + 3) / 4, 256, 0, stream>>>(bufA, v2s, v2d, asrc, adst, NN);
    gemm_bf16<0><<<dim3(391, 2), 256, 0, stream>>>(bufA, Wt2s, bufB, NN, 256, 512, nullptr, 0, 0);
    gat_pull<4><<<(NN + 3) / 4, 256, 0, stream>>>(ei1, rp1, eid1, ei2, rp2, eid2,
                                                  asrc, adst, bufB, b2, g2buf, NN);
    gemm_bf16<0><<<dim3(391, 2), 256, 0, stream>>>(g2buf, Wtl2, out, NN, 256, 256, bl2, 0, 1);

    (void)W1d; (void)a1d; (void)W2d; (void)a2d;
    (void)in_sizes; (void)n_in; (void)out_size; (void)ws_size;
}

// Round 5
// 635.846 us; speedup vs baseline: 1.3444x; 1.3444x over previous
//
#include <hip/hip_runtime.h>

typedef unsigned short u16;
typedef __attribute__((ext_vector_type(8))) unsigned short v8u16;
typedef __attribute__((ext_vector_type(4))) unsigned short v4u16;
typedef __attribute__((ext_vector_type(8))) __bf16 v8bf;
typedef __attribute__((ext_vector_type(4))) float v4f;

#define NN 50000
#define EE 150000

__device__ inline float b2f(u16 u) {
    union { unsigned int i; float f; } x; x.i = ((unsigned int)u) << 16; return x.f;
}
__device__ inline u16 f2b(float f) {
    union { float f; unsigned int i; } x; x.f = f;
    unsigned int r = x.i + 0x7FFFu + ((x.i >> 16) & 1u);
    return (u16)(r >> 16);
}
__device__ inline float wred(float v) {
    v += __shfl_down(v, 32, 64);
    v += __shfl_down(v, 16, 64);
    v += __shfl_down(v, 8, 64);
    v += __shfl_down(v, 4, 64);
    v += __shfl_down(v, 2, 64);
    v += __shfl_down(v, 1, 64);
    return v;
}

// ---------------- fused weight prep ----------------

// 4 transposes in one launch: Wt[n*K+k] = bf16(W[k*N+n])
__global__ void transpose4(const float* __restrict__ W0, u16* __restrict__ T0,
                           const float* __restrict__ W1, u16* __restrict__ T1,
                           const float* __restrict__ W2, u16* __restrict__ T2,
                           const float* __restrict__ W3, u16* __restrict__ T3) {
    int idx = blockIdx.x * blockDim.x + threadIdx.x;
    const float* W; u16* T; int N, K, base;
    if (idx < 262144)      { W = W0; T = T0; K = 512; N = 512; base = 0; }
    else if (idx < 524288) { W = W1; T = T1; K = 512; N = 512; base = 262144; }
    else if (idx < 655360) { W = W2; T = T2; K = 512; N = 256; base = 524288; }
    else if (idx < 720896) { W = W3; T = T3; K = 256; N = 256; base = 655360; }
    else return;
    int i = idx - base;
    int n = i % N, k = i / N;
    T[(size_t)n * K + k] = f2b(W[i]);
}

// 4 GEMVs v[r]=sum_c W[r*C+c]*a[c] in one launch; vbuf[seg*512+r]
__global__ void wv4(const float* __restrict__ Wa, const float* __restrict__ Wb,
                    const float* __restrict__ Wc, const float* __restrict__ Wd,
                    const float* __restrict__ aa, const float* __restrict__ ab,
                    const float* __restrict__ ac, const float* __restrict__ ad,
                    float* __restrict__ vbuf) {
    int rw = (blockIdx.x * blockDim.x + threadIdx.x) >> 6;  // 0..2047
    int lane = threadIdx.x & 63;
    if (rw >= 2048) return;
    int seg = rw >> 9, r = rw & 511;
    const float* W; const float* a; int C;
    if (seg == 0)      { W = Wa; a = aa; C = 512; }
    else if (seg == 1) { W = Wb; a = ab; C = 512; }
    else if (seg == 2) { W = Wc; a = ac; C = 256; }
    else               { W = Wd; a = ad; C = 256; }
    float s = 0.f;
    int c0 = lane * 8;
    if (c0 < C) {
        const float* wp = W + (size_t)r * C + c0;
        v4f w0 = *(const v4f*)wp;
        v4f w1 = *(const v4f*)(wp + 4);
        v4f a0 = *(const v4f*)(a + c0);
        v4f a1 = *(const v4f*)(a + c0 + 4);
#pragma unroll
        for (int j = 0; j < 4; ++j) s += w0[j] * a0[j] + w1[j] * a1[j];
    }
    s = wred(s);
    if (lane == 0) vbuf[rw] = s;
}

// asrc/adst GEMV pair + bf16 downcast of x (one wave per node, D=512)
__global__ void alpha_pair_f32x(const float* __restrict__ X, const float* __restrict__ vs,
                                const float* __restrict__ vd, float* __restrict__ as_,
                                float* __restrict__ ad_, u16* __restrict__ Xb, int Nn) {
    int w = (blockIdx.x * blockDim.x + threadIdx.x) >> 6;
    int lane = threadIdx.x & 63;
    if (w >= Nn) return;
    const float* xp = X + (size_t)w * 512 + lane * 8;
    v4f x0 = *(const v4f*)xp;
    v4f x1 = *(const v4f*)(xp + 4);
    const float* vsp = vs + lane * 8;
    const float* vdp = vd + lane * 8;
    float s1 = 0.f, s2 = 0.f;
    v8u16 o;
#pragma unroll
    for (int j = 0; j < 4; ++j) {
        s1 += x0[j] * vsp[j] + x1[j] * vsp[j + 4];
        s2 += x0[j] * vdp[j] + x1[j] * vdp[j + 4];
        o[j] = f2b(x0[j]); o[j + 4] = f2b(x1[j]);
    }
    *(v8u16*)(Xb + (size_t)w * 512 + lane * 8) = o;
    s1 = wred(s1);
    s2 = wred(s2);
    if (lane == 0) { as_[w] = s1; ad_[w] = s2; }
}

// bf16-X variant (layer 2)
__global__ void alpha_pair_bf16(const u16* __restrict__ X, const float* __restrict__ vs,
                                const float* __restrict__ vd, float* __restrict__ as_,
                                float* __restrict__ ad_, int Nn) {
    int w = (blockIdx.x * blockDim.x + threadIdx.x) >> 6;
    int lane = threadIdx.x & 63;
    if (w >= Nn) return;
    v8u16 xv = *(const v8u16*)(X + (size_t)w * 512 + lane * 8);
    const float* vsp = vs + lane * 8;
    const float* vdp = vd + lane * 8;
    float s1 = 0.f, s2 = 0.f;
#pragma unroll
    for (int j = 0; j < 8; ++j) {
        float xf = b2f(xv[j]);
        s1 += xf * vsp[j];
        s2 += xf * vdp[j];
    }
    s1 = wred(s1);
    s2 = wred(s2);
    if (lane == 0) { as_[w] = s1; ad_[w] = s2; }
}

// ---------------- CSR build, both edge sets fused ----------------

__global__ void deg2_kernel(const int* __restrict__ ei1, const int* __restrict__ ei2,
                            int* __restrict__ deg) {
    int idx = blockIdx.x * blockDim.x + threadIdx.x;
    if (idx >= 2 * EE) return;
    int set = idx >= EE;
    int e = idx - set * EE;
    const int* ei = set ? ei2 : ei1;
    atomicAdd(&deg[set * NN + ei[EE + e]], 1);
}

// grid=2 blocks; block b scans deg[b*NN..) into rp[b*(NN+1)..)
__global__ void exscan2_kernel(const int* __restrict__ deg, int* __restrict__ rp) {
    __shared__ int ls[1024];
    const int* d = deg + blockIdx.x * NN;
    int* r = rp + blockIdx.x * (NN + 1);
    int tid = threadIdx.x;
    int per = (NN + 1023) / 1024;
    int base = tid * per;
    int s = 0;
    for (int i = 0; i < per; ++i) if (base + i < NN) s += d[base + i];
    ls[tid] = s;
    __syncthreads();
    for (int off = 1; off < 1024; off <<= 1) {
        int v = (tid >= off) ? ls[tid - off] : 0;
        __syncthreads();
        ls[tid] += v;
        __syncthreads();
    }
    int run = ls[tid] - s;
    for (int i = 0; i < per; ++i) {
        if (base + i < NN) { r[base + i] = run; run += d[base + i]; }
    }
    if (tid == 1023) r[NN] = run;
}

// permuted edge arrays: srcp[set*EE+pos], dstp[set*EE+pos]
__global__ void fill2_kernel(const int* __restrict__ ei1, const int* __restrict__ ei2,
                             const int* __restrict__ rp, int* __restrict__ cursor,
                             int* __restrict__ srcp, int* __restrict__ dstp) {
    int idx = blockIdx.x * blockDim.x + threadIdx.x;
    if (idx >= 2 * EE) return;
    int set = idx >= EE;
    int e = idx - set * EE;
    const int* ei = set ? ei2 : ei1;
    int d = ei[EE + e];
    int pos = rp[set * (NN + 1) + d] + atomicAdd(&cursor[set * NN + d], 1);
    srcp[set * EE + pos] = ei[e];
    dstp[set * EE + pos] = d;
}

// per-layer edge weights: ex[i] = exp(leaky(asrc[src]+adst[dst])), both sets
__global__ void edge_ex(const int* __restrict__ srcp, const int* __restrict__ dstp,
                        const float* __restrict__ asrc, const float* __restrict__ adst,
                        float* __restrict__ ex) {
    int i = blockIdx.x * blockDim.x + threadIdx.x;
    if (i >= 2 * EE) return;
    float t = asrc[srcp[i]] + adst[dstp[i]];
    t = t > 0.f ? t : 0.2f * t;
    ex[i] = __expf(fminf(t, 60.f));
}

// ---------------- pull aggregate: one wave per dst node, single pass/set ----------------
template <int CV>
__global__ void gat_pull(const int* __restrict__ rp, const int* __restrict__ srcp,
                         const float* __restrict__ ex, const u16* __restrict__ H,
                         const float* __restrict__ bias, u16* __restrict__ G, int Nn) {
    const int C = CV * 64;
    int d = (blockIdx.x * blockDim.x + threadIdx.x) >> 6;
    int lane = threadIdx.x & 63;
    if (d >= Nn) return;
    float out[CV];
#pragma unroll
    for (int j = 0; j < CV; ++j) out[j] = 0.f;
#pragma unroll
    for (int set = 0; set < 2; ++set) {
        const int* rpS = rp + set * (NN + 1);
        int base = set * EE;
        int beg = rpS[d], end = rpS[d + 1];
        float acc[CV];
#pragma unroll
        for (int j = 0; j < CV; ++j) acc[j] = 0.f;
        float ssum = 0.f;
        for (int i = beg; i < end; ++i) {
            float w = ex[base + i];
            int s = srcp[base + i];
            ssum += w;
            const u16* hp = H + (size_t)s * C + lane * CV;
            if constexpr (CV == 8) {
                v8u16 hv = *(const v8u16*)hp;
#pragma unroll
                for (int j = 0; j < 8; ++j) acc[j] += w * b2f(hv[j]);
            } else {
                v4u16 hv = *(const v4u16*)hp;
#pragma unroll
                for (int j = 0; j < 4; ++j) acc[j] += w * b2f(hv[j]);
            }
        }
        float inv = 1.f / (ssum + 1e-16f);
#pragma unroll
        for (int j = 0; j < CV; ++j) out[j] += acc[j] * inv;
    }
    const float* bp = bias + lane * CV;
    u16* gp = G + (size_t)d * C + lane * CV;
    if constexpr (CV == 8) {
        v8u16 o;
#pragma unroll
        for (int j = 0; j < 8; ++j) o[j] = f2b(out[j] + 2.f * bp[j]);
        *(v8u16*)gp = o;
    } else {
        v4u16 o;
#pragma unroll
        for (int j = 0; j < 4; ++j) o[j] = f2b(out[j] + 2.f * bp[j]);
        *(v4u16*)gp = o;
    }
}

// ---------------- MFMA GEMM ----------------
// C[M,N] = A[M,K] @ Bt[N,K]^T. bf16 in, fp32 accum; out bf16 or fp32; bias/relu.
__global__ __launch_bounds__(256, 2) void gemm_bf16(
    const u16* __restrict__ A, const u16* __restrict__ Bt, void* __restrict__ Cv,
    int M, int N, int K, const float* __restrict__ bias, int relu, int outf32) {
    __shared__ u16 As[128 * 40];
    __shared__ u16 Bs[128 * 40];
    const int tid = threadIdx.x;
    const int lane = tid & 63;
    const int wid = tid >> 6;
    const int wm = wid >> 1;
    const int wn = wid & 1;
    const int quad = lane >> 4;
    const int l16 = lane & 15;
    const int tileM = blockIdx.x * 128;
    const int tileN = blockIdx.y * 128;

    v4f acc[4][4];
#pragma unroll
    for (int i = 0; i < 4; ++i)
#pragma unroll
        for (int j = 0; j < 4; ++j) acc[i][j] = v4f{0.f, 0.f, 0.f, 0.f};

    for (int k0 = 0; k0 < K; k0 += 32) {
#pragma unroll
        for (int r = 0; r < 2; ++r) {
            int idx = r * 256 + tid;
            int row = idx >> 2;
            int col = (idx & 3) << 3;
            int ga = tileM + row; ga = ga < M ? ga : M - 1;
            *(v8u16*)&As[row * 40 + col] = *(const v8u16*)(A + (size_t)ga * K + k0 + col);
            *(v8u16*)&Bs[row * 40 + col] = *(const v8u16*)(Bt + (size_t)(tileN + row) * K + k0 + col);
        }
        __syncthreads();
        v8bf af[4], bfr[4];
#pragma unroll
        for (int i = 0; i < 4; ++i)
            af[i] = __builtin_bit_cast(v8bf, *(const v8u16*)&As[(wm * 64 + i * 16 + l16) * 40 + quad * 8]);
#pragma unroll
        for (int i = 0; i < 4; ++i)
            bfr[i] = __builtin_bit_cast(v8bf, *(const v8u16*)&Bs[(wn * 64 + i * 16 + l16) * 40 + quad * 8]);
#pragma unroll
        for (int mi = 0; mi < 4; ++mi)
#pragma unroll
            for (int ni = 0; ni < 4; ++ni)
                acc[mi][ni] = __builtin_amdgcn_mfma_f32_16x16x32_bf16(af[mi], bfr[ni], acc[mi][ni], 0, 0, 0);
        __syncthreads();
    }

#pragma unroll
    for (int mi = 0; mi < 4; ++mi)
#pragma unroll
        for (int ni = 0; ni < 4; ++ni) {
            int col = tileN + wn * 64 + ni * 16 + l16;
            float bb = bias ? bias[col] : 0.f;
            int row0 = tileM + wm * 64 + mi * 16 + quad * 4;
#pragma unroll
            for (int r = 0; r < 4; ++r) {
                int row = row0 + r;
                if (row < M) {
                    float v = acc[mi][ni][r] + bb;
                    if (relu) v = fmaxf(v, 0.f);
                    if (outf32) ((float*)Cv)[(size_t)row * N + col] = v;
                    else        ((u16*)Cv)[(size_t)row * N + col] = f2b(v);
                }
            }
        }
}

// ---------------- launch ----------------

extern "C" void kernel_launch(void* const* d_in, const int* in_sizes, int n_in,
                              void* d_out, int out_size, void* d_ws, size_t ws_size,
                              hipStream_t stream) {
    const float* x  = (const float*)d_in[0];
    const int* ei1  = (const int*)d_in[1];
    const int* ei2  = (const int*)d_in[2];
    const float* W1s = (const float*)d_in[3];
    const float* W1d = (const float*)d_in[4];
    const float* a1s = (const float*)d_in[5];
    const float* a1d = (const float*)d_in[6];
    const float* b1  = (const float*)d_in[7];
    const float* Wl1 = (const float*)d_in[8];
    const float* bl1 = (const float*)d_in[9];
    const float* W2s = (const float*)d_in[10];
    const float* W2d = (const float*)d_in[11];
    const float* a2s = (const float*)d_in[12];
    const float* a2d = (const float*)d_in[13];
    const float* b2  = (const float*)d_in[14];
    const float* Wl2 = (const float*)d_in[15];
    const float* bl2 = (const float*)d_in[16];
    float* out = (float*)d_out;

    char* ws = (char*)d_ws;
    size_t off = 0;
    auto alloc = [&](size_t b) { void* p = ws + off; off = (off + b + 255) & ~(size_t)255; return p; };
    u16* bufA   = (u16*)alloc((size_t)NN * 512 * 2);   // Hsrc1 -> hmid
    u16* bufB   = (u16*)alloc((size_t)NN * 512 * 2);   // xb16 -> g1 -> Hsrc2(lo)+g2(hi)
    int* rp     = (int*)alloc((size_t)2 * (NN + 1) * 4);
    int* srcp   = (int*)alloc((size_t)2 * EE * 4);
    int* dstp   = (int*)alloc((size_t)2 * EE * 4);
    int* deg    = (int*)alloc((size_t)2 * NN * 4);     // reused as cursor
    float* ex   = (float*)alloc((size_t)2 * EE * 4);
    float* asrc = (float*)alloc((size_t)NN * 4);
    float* adst = (float*)alloc((size_t)NN * 4);
    float* vbuf = (float*)alloc(2048 * 4);             // v1s|v1d|v2s|v2d
    u16* Wt1s   = (u16*)alloc((size_t)512 * 512 * 2);
    u16* Wtl1   = (u16*)alloc((size_t)512 * 512 * 2);
    u16* Wt2s   = (u16*)alloc((size_t)512 * 256 * 2);
    u16* Wtl2   = (u16*)alloc((size_t)256 * 256 * 2);
    u16* g2buf  = bufB + (size_t)NN * 256;

    // CSR build (both sets)
    hipMemsetAsync(deg, 0, (size_t)2 * NN * 4, stream);
    deg2_kernel<<<(2 * EE + 255) / 256, 256, 0, stream>>>(ei1, ei2, deg);
    exscan2_kernel<<<2, 1024, 0, stream>>>(deg, rp);
    hipMemsetAsync(deg, 0, (size_t)2 * NN * 4, stream);
    fill2_kernel<<<(2 * EE + 255) / 256, 256, 0, stream>>>(ei1, ei2, rp, deg, srcp, dstp);

    // weight prep
    transpose4<<<(720896 + 255) / 256, 256, 0, stream>>>(W1s, Wt1s, Wl1, Wtl1, W2s, Wt2s, Wl2, Wtl2);
    wv4<<<512, 256, 0, stream>>>(W1s, W1d, W2s, W2d, a1s, a1d, a2s, a2d, vbuf);

    // ---- layer 1 ----
    alpha_pair_f32x<<<(NN + 3) / 4, 256, 0, stream>>>(x, vbuf, vbuf + 512, asrc, adst, bufB, NN);
    edge_ex<<<(2 * EE + 255) / 256, 256, 0, stream>>>(srcp, dstp, asrc, adst, ex);
    gemm_bf16<<<dim3(391, 4), 256, 0, stream>>>(bufB, Wt1s, bufA, NN, 512, 512, nullptr, 0, 0);
    gat_pull<8><<<(NN + 3) / 4, 256, 0, stream>>>(rp, srcp, ex, bufA, b1, bufB, NN);
    gemm_bf16<<<dim3(391, 4), 256, 0, stream>>>(bufB, Wtl1, bufA, NN, 512, 512, bl1, 1, 0);

    // ---- layer 2 ----
    alpha_pair_bf16<<<(NN + 3) / 4, 256, 0, stream>>>(bufA, vbuf + 1024, vbuf + 1536, asrc, adst, NN);
    edge_ex<<<(2 * EE + 255) / 256, 256, 0, stream>>>(srcp, dstp, asrc, adst, ex);
    gemm_bf16<<<dim3(391, 2), 256, 0, stream>>>(bufA, Wt2s, bufB, NN, 256, 512, nullptr, 0, 0);
    gat_pull<4><<<(NN + 3) / 4, 256, 0, stream>>>(rp, srcp, ex, bufB, b2, g2buf, NN);
    gemm_bf16<<<dim3(391, 2), 256, 0, stream>>>(g2buf, Wtl2, out, NN, 256, 256, bl2, 0, 1);

    (void)in_sizes; (void)n_in; (void)out_size; (void)ws_size;
}

// Round 6
// 551.904 us; speedup vs baseline: 1.5489x; 1.1521x over previous
//
#include <hip/hip_runtime.h>

typedef unsigned short u16;
typedef __attribute__((ext_vector_type(8))) unsigned short v8u16;
typedef __attribute__((ext_vector_type(4))) unsigned short v4u16;
typedef __attribute__((ext_vector_type(8))) __bf16 v8bf;
typedef __attribute__((ext_vector_type(4))) float v4f;

#define NN 50000
#define EE 150000
#define SCAN_CHUNK 512
#define NB_PER_SET 98   // ceil(NN / SCAN_CHUNK)

__device__ inline float b2f(u16 u) {
    union { unsigned int i; float f; } x; x.i = ((unsigned int)u) << 16; return x.f;
}
__device__ inline u16 f2b(float f) {
    union { float f; unsigned int i; } x; x.f = f;
    unsigned int r = x.i + 0x7FFFu + ((x.i >> 16) & 1u);
    return (u16)(r >> 16);
}
__device__ inline float wred(float v) {
    v += __shfl_down(v, 32, 64);
    v += __shfl_down(v, 16, 64);
    v += __shfl_down(v, 8, 64);
    v += __shfl_down(v, 4, 64);
    v += __shfl_down(v, 2, 64);
    v += __shfl_down(v, 1, 64);
    return v;
}
__device__ inline int wred_i(int v) {
    v += __shfl_down(v, 32, 64);
    v += __shfl_down(v, 16, 64);
    v += __shfl_down(v, 8, 64);
    v += __shfl_down(v, 4, 64);
    v += __shfl_down(v, 2, 64);
    v += __shfl_down(v, 1, 64);
    return v;
}

// ---------------- fused weight prep ----------------

__global__ void transpose4(const float* __restrict__ W0, u16* __restrict__ T0,
                           const float* __restrict__ W1, u16* __restrict__ T1,
                           const float* __restrict__ W2, u16* __restrict__ T2,
                           const float* __restrict__ W3, u16* __restrict__ T3) {
    int idx = blockIdx.x * blockDim.x + threadIdx.x;
    const float* W; u16* T; int N, K, base;
    if (idx < 262144)      { W = W0; T = T0; K = 512; N = 512; base = 0; }
    else if (idx < 524288) { W = W1; T = T1; K = 512; N = 512; base = 262144; }
    else if (idx < 655360) { W = W2; T = T2; K = 512; N = 256; base = 524288; }
    else if (idx < 720896) { W = W3; T = T3; K = 256; N = 256; base = 655360; }
    else return;
    int i = idx - base;
    int n = i % N, k = i / N;
    T[(size_t)n * K + k] = f2b(W[i]);
}

__global__ void wv4(const float* __restrict__ Wa, const float* __restrict__ Wb,
                    const float* __restrict__ Wc, const float* __restrict__ Wd,
                    const float* __restrict__ aa, const float* __restrict__ ab,
                    const float* __restrict__ ac, const float* __restrict__ ad,
                    float* __restrict__ vbuf) {
    int rw = (blockIdx.x * blockDim.x + threadIdx.x) >> 6;  // 0..2047
    int lane = threadIdx.x & 63;
    if (rw >= 2048) return;
    int seg = rw >> 9, r = rw & 511;
    const float* W; const float* a; int C;
    if (seg == 0)      { W = Wa; a = aa; C = 512; }
    else if (seg == 1) { W = Wb; a = ab; C = 512; }
    else if (seg == 2) { W = Wc; a = ac; C = 256; }
    else               { W = Wd; a = ad; C = 256; }
    float s = 0.f;
    int c0 = lane * 8;
    if (c0 < C) {
        const float* wp = W + (size_t)r * C + c0;
        v4f w0 = *(const v4f*)wp;
        v4f w1 = *(const v4f*)(wp + 4);
        v4f a0 = *(const v4f*)(a + c0);
        v4f a1 = *(const v4f*)(a + c0 + 4);
#pragma unroll
        for (int j = 0; j < 4; ++j) s += w0[j] * a0[j] + w1[j] * a1[j];
    }
    s = wred(s);
    if (lane == 0) vbuf[rw] = s;
}

// asrc/adst GEMV pair + bf16 downcast of x (one wave per node, D=512)
__global__ void alpha_pair_f32x(const float* __restrict__ X, const float* __restrict__ vs,
                                const float* __restrict__ vd, float* __restrict__ as_,
                                float* __restrict__ ad_, u16* __restrict__ Xb, int Nn) {
    int w = (blockIdx.x * blockDim.x + threadIdx.x) >> 6;
    int lane = threadIdx.x & 63;
    if (w >= Nn) return;
    const float* xp = X + (size_t)w * 512 + lane * 8;
    v4f x0 = *(const v4f*)xp;
    v4f x1 = *(const v4f*)(xp + 4);
    const float* vsp = vs + lane * 8;
    const float* vdp = vd + lane * 8;
    float s1 = 0.f, s2 = 0.f;
    v8u16 o;
#pragma unroll
    for (int j = 0; j < 4; ++j) {
        s1 += x0[j] * vsp[j] + x1[j] * vsp[j + 4];
        s2 += x0[j] * vdp[j] + x1[j] * vdp[j + 4];
        o[j] = f2b(x0[j]); o[j + 4] = f2b(x1[j]);
    }
    *(v8u16*)(Xb + (size_t)w * 512 + lane * 8) = o;
    s1 = wred(s1);
    s2 = wred(s2);
    if (lane == 0) { as_[w] = s1; ad_[w] = s2; }
}

// bf16-X variant (layer 2)
__global__ void alpha_pair_bf16(const u16* __restrict__ X, const float* __restrict__ vs,
                                const float* __restrict__ vd, float* __restrict__ as_,
                                float* __restrict__ ad_, int Nn) {
    int w = (blockIdx.x * blockDim.x + threadIdx.x) >> 6;
    int lane = threadIdx.x & 63;
    if (w >= Nn) return;
    v8u16 xv = *(const v8u16*)(X + (size_t)w * 512 + lane * 8);
    const float* vsp = vs + lane * 8;
    const float* vdp = vd + lane * 8;
    float s1 = 0.f, s2 = 0.f;
#pragma unroll
    for (int j = 0; j < 8; ++j) {
        float xf = b2f(xv[j]);
        s1 += xf * vsp[j];
        s2 += xf * vdp[j];
    }
    s1 = wred(s1);
    s2 = wred(s2);
    if (lane == 0) { as_[w] = s1; ad_[w] = s2; }
}

// ---------------- CSR build, both edge sets fused ----------------

__global__ void deg2_kernel(const int* __restrict__ ei1, const int* __restrict__ ei2,
                            int* __restrict__ deg) {
    int idx = blockIdx.x * blockDim.x + threadIdx.x;
    if (idx >= 2 * EE) return;
    int set = idx >= EE;
    int e = idx - set * EE;
    const int* ei = set ? ei2 : ei1;
    atomicAdd(&deg[set * NN + ei[EE + e]], 1);
}

// multi-block exclusive scan of deg (2 independent segments of NN) -> rp
// pass 1: per-block (512-elem chunk) sums
__global__ void scan_partial(const int* __restrict__ deg, int* __restrict__ bsum) {
    int b = blockIdx.x;                       // 0..2*NB_PER_SET-1
    int set = b / NB_PER_SET, lb = b - set * NB_PER_SET;
    int tid = threadIdx.x;                    // 256
    int i0 = lb * SCAN_CHUNK + tid * 2;
    int s = 0;
    if (i0 < NN)     s += deg[set * NN + i0];
    if (i0 + 1 < NN) s += deg[set * NN + i0 + 1];
    s = wred_i(s);
    __shared__ int lsum[4];
    if ((tid & 63) == 0) lsum[tid >> 6] = s;
    __syncthreads();
    if (tid == 0) bsum[b] = lsum[0] + lsum[1] + lsum[2] + lsum[3];
}

// pass 2: one block; exclusive scan of the 98 block sums within each set
__global__ void scan_tops(int* __restrict__ bsum) {
    __shared__ int ls[256];
    int tid = threadIdx.x;                    // 256 = 2 sets x 128 slots
    int set = tid >> 7, lb = tid & 127;
    int v = (lb < NB_PER_SET) ? bsum[set * NB_PER_SET + lb] : 0;
    ls[tid] = v;
    __syncthreads();
    for (int off = 1; off < 128; off <<= 1) {
        int t = (lb >= off) ? ls[tid - off] : 0;
        __syncthreads();
        ls[tid] += t;
        __syncthreads();
    }
    if (lb < NB_PER_SET) bsum[set * NB_PER_SET + lb] = ls[tid] - v;  // exclusive
}

// pass 3: per-block local exclusive scan + block offset -> rp
__global__ void scan_final(const int* __restrict__ deg, const int* __restrict__ bsum,
                           int* __restrict__ rp) {
    int b = blockIdx.x;
    int set = b / NB_PER_SET, lb = b - set * NB_PER_SET;
    int tid = threadIdx.x;                    // 256
    int i0 = lb * SCAN_CHUNK + tid * 2;
    int d0 = (i0 < NN)     ? deg[set * NN + i0]     : 0;
    int d1 = (i0 + 1 < NN) ? deg[set * NN + i0 + 1] : 0;
    int pair = d0 + d1;
    __shared__ int ps[256];
    ps[tid] = pair;
    __syncthreads();
    for (int off = 1; off < 256; off <<= 1) {
        int t = (tid >= off) ? ps[tid - off] : 0;
        __syncthreads();
        ps[tid] += t;
        __syncthreads();
    }
    int base = bsum[b] + ps[tid] - pair;      // exclusive over this block's pairs
    if (i0 < NN)     rp[set * (NN + 1) + i0] = base;
    if (i0 + 1 < NN) rp[set * (NN + 1) + i0 + 1] = base + d0;
    if (b == 0 && tid == 0) { rp[NN] = EE; rp[(NN + 1) + NN] = EE; }
}

// fill permuted edge arrays; consumes deg via atomicSub (no cursor/memset needed)
__global__ void fill2_kernel(const int* __restrict__ ei1, const int* __restrict__ ei2,
                             const int* __restrict__ rp, int* __restrict__ deg,
                             int* __restrict__ srcp, int* __restrict__ dstp) {
    int idx = blockIdx.x * blockDim.x + threadIdx.x;
    if (idx >= 2 * EE) return;
    int set = idx >= EE;
    int e = idx - set * EE;
    const int* ei = set ? ei2 : ei1;
    int d = ei[EE + e];
    int old = atomicSub(&deg[set * NN + d], 1);
    int pos = rp[set * (NN + 1) + d] + old - 1;
    srcp[set * EE + pos] = ei[e];
    dstp[set * EE + pos] = d;
}

// per-layer edge weights: ex[i] = exp(leaky(asrc[src]+adst[dst])), both sets
__global__ void edge_ex(const int* __restrict__ srcp, const int* __restrict__ dstp,
                        const float* __restrict__ asrc, const float* __restrict__ adst,
                        float* __restrict__ ex) {
    int i = blockIdx.x * blockDim.x + threadIdx.x;
    if (i >= 2 * EE) return;
    float t = asrc[srcp[i]] + adst[dstp[i]];
    t = t > 0.f ? t : 0.2f * t;
    ex[i] = __expf(fminf(t, 60.f));
}

// ---------------- pull aggregate: one wave per dst node, single pass/set ----------------
template <int CV>
__global__ void gat_pull(const int* __restrict__ rp, const int* __restrict__ srcp,
                         const float* __restrict__ ex, const u16* __restrict__ H,
                         const float* __restrict__ bias, u16* __restrict__ G, int Nn) {
    const int C = CV * 64;
    int d = (blockIdx.x * blockDim.x + threadIdx.x) >> 6;
    int lane = threadIdx.x & 63;
    if (d >= Nn) return;
    float out[CV];
#pragma unroll
    for (int j = 0; j < CV; ++j) out[j] = 0.f;
#pragma unroll
    for (int set = 0; set < 2; ++set) {
        const int* rpS = rp + set * (NN + 1);
        int base = set * EE;
        int beg = rpS[d], end = rpS[d + 1];
        float acc[CV];
#pragma unroll
        for (int j = 0; j < CV; ++j) acc[j] = 0.f;
        float ssum = 0.f;
        for (int i = beg; i < end; ++i) {
            float w = ex[base + i];
            int s = srcp[base + i];
            ssum += w;
            const u16* hp = H + (size_t)s * C + lane * CV;
            if constexpr (CV == 8) {
                v8u16 hv = *(const v8u16*)hp;
#pragma unroll
                for (int j = 0; j < 8; ++j) acc[j] += w * b2f(hv[j]);
            } else {
                v4u16 hv = *(const v4u16*)hp;
#pragma unroll
                for (int j = 0; j < 4; ++j) acc[j] += w * b2f(hv[j]);
            }
        }
        float inv = 1.f / (ssum + 1e-16f);
#pragma unroll
        for (int j = 0; j < CV; ++j) out[j] += acc[j] * inv;
    }
    const float* bp = bias + lane * CV;
    u16* gp = G + (size_t)d * C + lane * CV;
    if constexpr (CV == 8) {
        v8u16 o;
#pragma unroll
        for (int j = 0; j < 8; ++j) o[j] = f2b(out[j] + 2.f * bp[j]);
        *(v8u16*)gp = o;
    } else {
        v4u16 o;
#pragma unroll
        for (int j = 0; j < 4; ++j) o[j] = f2b(out[j] + 2.f * bp[j]);
        *(v4u16*)gp = o;
    }
}

// ---------------- MFMA GEMM ----------------
// C[M,N] = A[M,K] @ Bt[N,K]^T. bf16 in, fp32 accum; out bf16 or fp32; bias/relu.
__global__ __launch_bounds__(256, 2) void gemm_bf16(
    const u16* __restrict__ A, const u16* __restrict__ Bt, void* __restrict__ Cv,
    int M, int N, int K, const float* __restrict__ bias, int relu, int outf32) {
    __shared__ u16 As[128 * 40];
    __shared__ u16 Bs[128 * 40];
    const int tid = threadIdx.x;
    const int lane = tid & 63;
    const int wid = tid >> 6;
    const int wm = wid >> 1;
    const int wn = wid & 1;
    const int quad = lane >> 4;
    const int l16 = lane & 15;
    const int tileM = blockIdx.x * 128;
    const int tileN = blockIdx.y * 128;

    v4f acc[4][4];
#pragma unroll
    for (int i = 0; i < 4; ++i)
#pragma unroll
        for (int j = 0; j < 4; ++j) acc[i][j] = v4f{0.f, 0.f, 0.f, 0.f};

    for (int k0 = 0; k0 < K; k0 += 32) {
#pragma unroll
        for (int r = 0; r < 2; ++r) {
            int idx = r * 256 + tid;
            int row = idx >> 2;
            int col = (idx & 3) << 3;
            int ga = tileM + row; ga = ga < M ? ga : M - 1;
            *(v8u16*)&As[row * 40 + col] = *(const v8u16*)(A + (size_t)ga * K + k0 + col);
            *(v8u16*)&Bs[row * 40 + col] = *(const v8u16*)(Bt + (size_t)(tileN + row) * K + k0 + col);
        }
        __syncthreads();
        v8bf af[4], bfr[4];
#pragma unroll
        for (int i = 0; i < 4; ++i)
            af[i] = __builtin_bit_cast(v8bf, *(const v8u16*)&As[(wm * 64 + i * 16 + l16) * 40 + quad * 8]);
#pragma unroll
        for (int i = 0; i < 4; ++i)
            bfr[i] = __builtin_bit_cast(v8bf, *(const v8u16*)&Bs[(wn * 64 + i * 16 + l16) * 40 + quad * 8]);
#pragma unroll
        for (int mi = 0; mi < 4; ++mi)
#pragma unroll
            for (int ni = 0; ni < 4; ++ni)
                acc[mi][ni] = __builtin_amdgcn_mfma_f32_16x16x32_bf16(af[mi], bfr[ni], acc[mi][ni], 0, 0, 0);
        __syncthreads();
    }

#pragma unroll
    for (int mi = 0; mi < 4; ++mi)
#pragma unroll
        for (int ni = 0; ni < 4; ++ni) {
            int col = tileN + wn * 64 + ni * 16 + l16;
            float bb = bias ? bias[col] : 0.f;
            int row0 = tileM + wm * 64 + mi * 16 + quad * 4;
#pragma unroll
            for (int r = 0; r < 4; ++r) {
                int row = row0 + r;
                if (row < M) {
                    float v = acc[mi][ni][r] + bb;
                    if (relu) v = fmaxf(v, 0.f);
                    if (outf32) ((float*)Cv)[(size_t)row * N + col] = v;
                    else        ((u16*)Cv)[(size_t)row * N + col] = f2b(v);
                }
            }
        }
}

// ---------------- launch ----------------

extern "C" void kernel_launch(void* const* d_in, const int* in_sizes, int n_in,
                              void* d_out, int out_size, void* d_ws, size_t ws_size,
                              hipStream_t stream) {
    const float* x  = (const float*)d_in[0];
    const int* ei1  = (const int*)d_in[1];
    const int* ei2  = (const int*)d_in[2];
    const float* W1s = (const float*)d_in[3];
    const float* W1d = (const float*)d_in[4];
    const float* a1s = (const float*)d_in[5];
    const float* a1d = (const float*)d_in[6];
    const float* b1  = (const float*)d_in[7];
    const float* Wl1 = (const float*)d_in[8];
    const float* bl1 = (const float*)d_in[9];
    const float* W2s = (const float*)d_in[10];
    const float* W2d = (const float*)d_in[11];
    const float* a2s = (const float*)d_in[12];
    const float* a2d = (const float*)d_in[13];
    const float* b2  = (const float*)d_in[14];
    const float* Wl2 = (const float*)d_in[15];
    const float* bl2 = (const float*)d_in[16];
    float* out = (float*)d_out;

    char* ws = (char*)d_ws;
    size_t off = 0;
    auto alloc = [&](size_t b) { void* p = ws + off; off = (off + b + 255) & ~(size_t)255; return p; };
    u16* bufA   = (u16*)alloc((size_t)NN * 512 * 2);   // Hsrc1 -> hmid
    u16* bufB   = (u16*)alloc((size_t)NN * 512 * 2);   // xb16 -> g1 -> Hsrc2(lo)+g2(hi)
    int* rp     = (int*)alloc((size_t)2 * (NN + 1) * 4);
    int* srcp   = (int*)alloc((size_t)2 * EE * 4);
    int* dstp   = (int*)alloc((size_t)2 * EE * 4);
    int* deg    = (int*)alloc((size_t)2 * NN * 4);
    int* bsum   = (int*)alloc((size_t)2 * NB_PER_SET * 4);
    float* ex   = (float*)alloc((size_t)2 * EE * 4);
    float* asrc = (float*)alloc((size_t)NN * 4);
    float* adst = (float*)alloc((size_t)NN * 4);
    float* vbuf = (float*)alloc(2048 * 4);             // v1s|v1d|v2s|v2d
    u16* Wt1s   = (u16*)alloc((size_t)512 * 512 * 2);
    u16* Wtl1   = (u16*)alloc((size_t)512 * 512 * 2);
    u16* Wt2s   = (u16*)alloc((size_t)512 * 256 * 2);
    u16* Wtl2   = (u16*)alloc((size_t)256 * 256 * 2);
    u16* g2buf  = bufB + (size_t)NN * 256;

    // CSR build (both sets)
    hipMemsetAsync(deg, 0, (size_t)2 * NN * 4, stream);
    deg2_kernel<<<(2 * EE + 255) / 256, 256, 0, stream>>>(ei1, ei2, deg);
    scan_partial<<<2 * NB_PER_SET, 256, 0, stream>>>(deg, bsum);
    scan_tops<<<1, 256, 0, stream>>>(bsum);
    scan_final<<<2 * NB_PER_SET, 256, 0, stream>>>(deg, bsum, rp);
    fill2_kernel<<<(2 * EE + 255) / 256, 256, 0, stream>>>(ei1, ei2, rp, deg, srcp, dstp);

    // weight prep
    transpose4<<<(720896 + 255) / 256, 256, 0, stream>>>(W1s, Wt1s, Wl1, Wtl1, W2s, Wt2s, Wl2, Wtl2);
    wv4<<<512, 256, 0, stream>>>(W1s, W1d, W2s, W2d, a1s, a1d, a2s, a2d, vbuf);

    // ---- layer 1 ----
    alpha_pair_f32x<<<(NN + 3) / 4, 256, 0, stream>>>(x, vbuf, vbuf + 512, asrc, adst, bufB, NN);
    edge_ex<<<(2 * EE + 255) / 256, 256, 0, stream>>>(srcp, dstp, asrc, adst, ex);
    gemm_bf16<<<dim3(391, 4), 256, 0, stream>>>(bufB, Wt1s, bufA, NN, 512, 512, nullptr, 0, 0);
    gat_pull<8><<<(NN + 3) / 4, 256, 0, stream>>>(rp, srcp, ex, bufA, b1, bufB, NN);
    gemm_bf16<<<dim3(391, 4), 256, 0, stream>>>(bufB, Wtl1, bufA, NN, 512, 512, bl1, 1, 0);

    // ---- layer 2 ----
    alpha_pair_bf16<<<(NN + 3) / 4, 256, 0, stream>>>(bufA, vbuf + 1024, vbuf + 1536, asrc, adst, NN);
    edge_ex<<<(2 * EE + 255) / 256, 256, 0, stream>>>(srcp, dstp, asrc, adst, ex);
    gemm_bf16<<<dim3(391, 2), 256, 0, stream>>>(bufA, Wt2s, bufB, NN, 256, 512, nullptr, 0, 0);
    gat_pull<4><<<(NN + 3) / 4, 256, 0, stream>>>(rp, srcp, ex, bufB, b2, g2buf, NN);
    gemm_bf16<<<dim3(391, 2), 256, 0, stream>>>(g2buf, Wtl2, out, NN, 256, 256, bl2, 0, 1);

    (void)in_sizes; (void)n_in; (void)out_size; (void)ws_size;
}